// Round 6
// baseline (233.292 us; speedup 1.0000x reference)
//
#include <hip/hip_runtime.h>
#include <hip/hip_bf16.h>
#include <math.h>

#define EMBED 768
#define NHEAD 12
#define HDIM 64
#define SEQ 2048
#define BATCH 4

typedef __hip_bfloat16 bf16;
typedef __attribute__((ext_vector_type(8))) short bf16x8;   // 8 bf16 / 4 VGPRs
typedef __attribute__((ext_vector_type(4))) short s16x4;
typedef __attribute__((ext_vector_type(4))) float f32x4;
typedef __attribute__((ext_vector_type(2))) unsigned int u32x2;

__device__ inline float b2f(bf16 v) { return __bfloat162float(v); }
__device__ inline bf16 f2b(float v) { return __float2bfloat16(v); }
__device__ inline unsigned pk2(float a, float b) {
  return (unsigned)__bfloat16_as_ushort(f2b(a)) |
         ((unsigned)__bfloat16_as_ushort(f2b(b)) << 16);
}

// async global->LDS, 16B per lane. LDS dest = wave-uniform base + lane*16.
__device__ inline void gl_lds16(const bf16* g, bf16* l) {
  __builtin_amdgcn_global_load_lds(
      (const __attribute__((address_space(1))) void*)g,
      (__attribute__((address_space(3))) void*)l, 16, 0, 0);
}

#define NX4  (BATCH * SEQ * EMBED / 4)
#define NWQ4 (3 * EMBED * EMBED / 4)
#define NWP4 (EMBED * EMBED / 4)

// ---------------------------------------------------------------------------
// One fused f32->bf16 convert for x, w_qkv, w_proj (segmented index space).
// ---------------------------------------------------------------------------
__global__ __launch_bounds__(256) void cvt_all(
    const float* __restrict__ x, const float* __restrict__ wq,
    const float* __restrict__ wp, bf16* __restrict__ xb,
    bf16* __restrict__ wqb, bf16* __restrict__ wpb) {
  int i = blockIdx.x * 256 + threadIdx.x;
  const float* src;
  bf16* dst;
  int k;
  if (i < NX4) {
    src = x; dst = xb; k = i;
  } else if (i < NX4 + NWQ4) {
    src = wq; dst = wqb; k = i - NX4;
  } else if (i < NX4 + NWQ4 + NWP4) {
    src = wp; dst = wpb; k = i - NX4 - NWQ4;
  } else {
    return;
  }
  float4 v = ((const float4*)src)[k];
  s16x4 o;
  o[0] = (short)__bfloat16_as_ushort(f2b(v.x));
  o[1] = (short)__bfloat16_as_ushort(f2b(v.y));
  o[2] = (short)__bfloat16_as_ushort(f2b(v.z));
  o[3] = (short)__bfloat16_as_ushort(f2b(v.w));
  *(s16x4*)(dst + 4 * (size_t)k) = o;
}

// ---------------------------------------------------------------------------
// R18: QKV GEMM rebuilt as 256x256-tile, 512-thread / 8-wave, 2-phase
//   double-buffered (T3-minimum recipe, R3's race-audited pattern):
//   per step: STAGE(t+1 -> buf p^1) issued FIRST, compute(t from buf p)
//   [24 ds_read_b128 + 64 MFMA per wave], then ONE __syncthreads
//   (= vmcnt(0)+lgkmcnt(0)+s_barrier: drains t+1's DMA AND provides WAR).
//   Mechanism vs R3's null at 128^2: per-step compute window is now
//   ~2500 cy/CU (512 MFMA) >> HBM latency (~900 cy), so the prefetch
//   actually covers the loads; barrier/drain amortized 4x better.
//   Reference quadrant (learn_hip m230): 256^2+2ph = 666-682 TF vs our
//   measured ~310-450.  Grid 9x32 = 288 blocks, 128 KB LDS -> 1 block/CU.
//   __launch_bounds__(512,2) caps VGPR at 256 (acc[4][8]=128 + frags 48).
// Epilogue (MODE-0, verified R11/R12): scatter Q(x 0.125*log2e)->[B,H,N,D],
//   K->[B,H,N,D], V->[B,H,D,N] (bf16). Same formulas, j now 0..7.
// R14 (kept): BK=64, both-sides XOR swizzle — DMA source chunk
//   (lane&7)^(lane>>3), read slot (h*4+g)^(c&7).
// ---------------------------------------------------------------------------
__global__ __launch_bounds__(512, 2) void gemm_qkv(
    const bf16* __restrict__ A, const bf16* __restrict__ W,
    const float* __restrict__ bias, bf16* __restrict__ outQ,
    bf16* __restrict__ outK, bf16* __restrict__ outV, int K) {
  __shared__ bf16 As[2][256][64];
  __shared__ bf16 Bs[2][256][64];
  const int t = threadIdx.x;
  const int w = t >> 6;                // 0..7
  const int lane = t & 63;
  const int g = lane >> 4, c = lane & 15;
  const int m0 = blockIdx.y * 256, n0 = blockIdx.x * 256;
  const int wr = (w >> 2) * 128;       // m-dim tile base (As): 2 wave-rows
  const int wc = (w & 3) * 64;         // o-dim tile base (Bs): 4 wave-cols

  // DMA mapping: 1KB per instr = 8 rows x 128B. Source chunk pre-swizzled.
  const int srow = lane >> 3;          // 0..7 row within 8-row stripe
  const int l8 = lane & 7;             // LDS 16B-slot within row
  const int sseg = (l8 ^ srow) * 8;    // swizzled global chunk (bf16 elems)

  f32x4 acc[4][8] = {};   // acc[i][j]: i over o-tiles (W), j over m-tiles (x)
  const int nsteps = K >> 6;           // K=768 -> 12

  // prologue: stage step 0 into buf 0, drain before first use
#pragma unroll
  for (int i = 0; i < 4; i++) {
    int r = w * 32 + i * 8;
    gl_lds16(A + (size_t)(m0 + r + srow) * K + sseg, &As[0][r][0]);
    gl_lds16(W + (size_t)(n0 + r + srow) * K + sseg, &Bs[0][r][0]);
  }
  __syncthreads();

  for (int s = 0; s < nsteps; s++) {
    const int p = s & 1;
    // issue next step's stage FIRST — lands under this step's ~2500cy compute
    if (s + 1 < nsteps) {
      const int k0 = (s + 1) << 6;
#pragma unroll
      for (int i = 0; i < 4; i++) {
        int r = w * 32 + i * 8;
        gl_lds16(A + (size_t)(m0 + r + srow) * K + k0 + sseg, &As[p ^ 1][r][0]);
        gl_lds16(W + (size_t)(n0 + r + srow) * K + k0 + sseg, &Bs[p ^ 1][r][0]);
      }
    }

#pragma unroll
    for (int h = 0; h < 2; h++) {
      bf16x8 xf[8], wf[4];
#pragma unroll
      for (int j = 0; j < 8; j++)
        xf[j] = *(const bf16x8*)&As[p][wr + j * 16 + c][((h * 4 + g) ^ (c & 7)) * 8];
#pragma unroll
      for (int i = 0; i < 4; i++)
        wf[i] = *(const bf16x8*)&Bs[p][wc + i * 16 + c][((h * 4 + g) ^ (c & 7)) * 8];
#pragma unroll
      for (int i = 0; i < 4; i++)
#pragma unroll
        for (int j = 0; j < 8; j++)
          acc[i][j] = __builtin_amdgcn_mfma_f32_16x16x32_bf16(wf[i], xf[j],
                                                              acc[i][j], 0, 0, 0);
    }
    // single barrier: (a) WAR for buf p before s+1 overwrites it at s+2,
    // (b) vmcnt(0) drains the s+1 stage issued above.
    __syncthreads();
  }

  // epilogue: D^T tile — row = o (4 consecutive per thread), col = m (lane c)
#pragma unroll
  for (int i = 0; i < 4; i++) {
    const int ob = n0 + wc + i * 16 + g * 4;     // o base, +r consecutive
    const f32x4 bv = *(const f32x4*)&bias[ob];   // 16B-aligned
    const int which = ob / EMBED;                // uniform per i (256|768 ok)
    const int rem = ob - which * EMBED;
    const int hh = rem >> 6;
    const int d0 = rem & 63;
#pragma unroll
    for (int j = 0; j < 8; j++) {
      const int m = m0 + wr + j * 16 + c;
      f32x4 v = acc[i][j] + bv;
      const int bb = m >> 11, n = m & 2047;
      const size_t bh = (size_t)bb * NHEAD + hh;
      if (which == 0) {
        s16x4 q4;
#pragma unroll
        for (int r = 0; r < 4; r++)
          q4[r] = (short)__bfloat16_as_ushort(f2b(v[r] * 0.1803368801f));
        *(s16x4*)&outQ[(bh * SEQ + n) * HDIM + d0] = q4;
      } else if (which == 1) {
        s16x4 k4;
#pragma unroll
        for (int r = 0; r < 4; r++)
          k4[r] = (short)__bfloat16_as_ushort(f2b(v[r]));
        *(s16x4*)&outK[(bh * SEQ + n) * HDIM + d0] = k4;
      } else {
#pragma unroll
        for (int r = 0; r < 4; r++)
          outV[(bh * HDIM + d0 + r) * SEQ + n] = f2b(v[r]);
      }
    }
  }
}

// ---------------------------------------------------------------------------
// proj GEMM — R5-verified 128xTM structure (single-buf BK=64, 2 barriers,
// both-sides XOR swizzle, launch_bounds(256,4)). TM=64: grid 768 blocks
// (TM=128 was grid-starved at 384). outF[m,o] f32 row-major.
// ---------------------------------------------------------------------------
template <int TM>
__global__ __launch_bounds__(256, 4) void gemm_proj(
    const bf16* __restrict__ A, const bf16* __restrict__ W,
    const float* __restrict__ bias, float* __restrict__ outF, int N, int K) {
  __shared__ bf16 As[TM][64];
  __shared__ bf16 Bs[128][64];
  const int t = threadIdx.x;
  const int w = t >> 6;
  const int lane = t & 63;
  const int g = lane >> 4, c = lane & 15;
  const int m0 = blockIdx.y * TM, n0 = blockIdx.x * 128;
  constexpr int MJ = TM / 32;          // m-frags per wave: 2 (TM=64)
  const int wr = (w >> 1) * (TM / 2);  // m-dim tile base (As)
  const int wc = (w & 1) * 64;         // o-dim tile base (Bs)

  const int srow = lane >> 3;
  const int l8 = lane & 7;
  const int sseg = (l8 ^ srow) * 8;

  f32x4 acc[4][MJ] = {};

  for (int k0 = 0; k0 < K; k0 += 64) {
#pragma unroll
    for (int i = 0; i < 4; i++) {
      int r = w * 32 + i * 8;
      gl_lds16(W + (size_t)(n0 + r + srow) * K + k0 + sseg, &Bs[r][0]);
    }
#pragma unroll
    for (int i = 0; i < TM / 32; i++) {
      int r = w * (TM / 4) + i * 8;
      gl_lds16(A + (size_t)(m0 + r + srow) * K + k0 + sseg, &As[r][0]);
    }
    __syncthreads();

#pragma unroll
    for (int h = 0; h < 2; h++) {
      bf16x8 xf[MJ], wf[4];
#pragma unroll
      for (int j = 0; j < MJ; j++)
        xf[j] = *(const bf16x8*)&As[wr + j * 16 + c][((h * 4 + g) ^ (c & 7)) * 8];
#pragma unroll
      for (int i = 0; i < 4; i++)
        wf[i] = *(const bf16x8*)&Bs[wc + i * 16 + c][((h * 4 + g) ^ (c & 7)) * 8];
#pragma unroll
      for (int i = 0; i < 4; i++)
#pragma unroll
        for (int j = 0; j < MJ; j++)
          acc[i][j] = __builtin_amdgcn_mfma_f32_16x16x32_bf16(wf[i], xf[j],
                                                              acc[i][j], 0, 0, 0);
    }
    __syncthreads();
  }

#pragma unroll
  for (int i = 0; i < 4; i++) {
    const int ob = n0 + wc + i * 16 + g * 4;
    const f32x4 bv = *(const f32x4*)&bias[ob];
#pragma unroll
    for (int j = 0; j < MJ; j++) {
      const int m = m0 + wr + j * 16 + c;
      f32x4 v = acc[i][j] + bv;
      *(f32x4*)&outF[(size_t)m * N + ob] = v;
    }
  }
}

// ---------------------------------------------------------------------------
// Flash MFMA attention v7 — measured-best structure (82.3-83.4 µs), FROZEN.
// R14 post-mortem: v8 (dbuf + single barrier + setprio) was NULL-to-negative
// (84.7 µs) — attn is not barrier/drain-bound; plateau is structural
// (LDS traffic + 3 waves/SIMD latency hiding).
//   S^T = K . Q^T ; O^T = V^T . P^T  (fragment maps verified R3-R12)
// Block = 128 q-rows, 4 waves x 2 groups of 16. LDS 34.8 KB; grid 768 = 3/CU.
// Per iter: S(ks) -> B1 -> DMA K(jt+1) -> softmax/Pt/PV(vs) -> B2 -> DMA V(jt+1).
// ---------------------------------------------------------------------------
__global__ __launch_bounds__(256, 4) void attn_mfma(
    const bf16* __restrict__ Q, const bf16* __restrict__ Kk,
    const bf16* __restrict__ V, bf16* __restrict__ O) {
  __shared__ bf16 Ks[64 * 64];
  __shared__ bf16 Vts[64 * 64];
  __shared__ bf16 Pt[8][16 * 72];

  const int blk = blockIdx.x;
  const int bh = blk >> 4;               // 16 q-tiles (of 128) per (b,h)
  const int qt = blk & 15;
  const int bb = bh / NHEAD;
  const int h = bh % NHEAD;
  const int t = threadIdx.x;
  const int lane = t & 63;
  const int w = t >> 6;
  const int g = lane >> 4;
  const int c = lane & 15;
  const size_t base = (size_t)bh * SEQ * HDIM;
  const int mb0 = qt * 128 + w * 16;     // q-group 0 rows
  const int mb1 = mb0 + 64;              // q-group 1 rows

  // DMA lane mapping (XOR chunk swizzle for K/V, verified R5-R12)
  const int r8 = lane >> 3;
  const int l8 = lane & 7;
  const int gch = l8 ^ (r8 & 7);
  const int q0 = w * 2, q1 = w * 2 + 1;

  // Q fragments (B operand), one pair per q-group
  bf16x8 qa[2][2];
#pragma unroll
  for (int kh = 0; kh < 2; kh++) {
    qa[0][kh] = *(const bf16x8*)(Q + base + (size_t)(mb0 + c) * HDIM + kh * 32 + g * 8);
    qa[1][kh] = *(const bf16x8*)(Q + base + (size_t)(mb1 + c) * HDIM + kh * 32 + g * 8);
  }

  // all-ones A fragment for the l-row-sum MFMA
  bf16x8 ones;
#pragma unroll
  for (int i = 0; i < 8; i++) ones[i] = (short)0x3F80;

  f32x4 o[2][4] = {};
  f32x4 o_l[2] = {};

  // prologue: DMA tile 0 (K and V), drain before first use
  gl_lds16(Kk + base + (size_t)(q0 * 8 + r8) * HDIM + gch * 8, &Ks[q0 * 8 * 64]);
  gl_lds16(Kk + base + (size_t)(q1 * 8 + r8) * HDIM + gch * 8, &Ks[q1 * 8 * 64]);
  gl_lds16(V + base + (size_t)(q0 * 8 + r8) * SEQ + gch * 8, &Vts[q0 * 8 * 64]);
  gl_lds16(V + base + (size_t)(q1 * 8 + r8) * SEQ + gch * 8, &Vts[q1 * 8 * 64]);
  __syncthreads();

  bf16* const Pt0 = Pt[w * 2];
  bf16* const Pt1 = Pt[w * 2 + 1];

  for (int jt = 0; jt < SEQ / 64; jt++) {
    // S^T = K . Q^T — each kb read feeds both q-groups
    f32x4 s[2][4] = {};
#pragma unroll
    for (int nt = 0; nt < 4; nt++) {
#pragma unroll
      for (int kh = 0; kh < 2; kh++) {
        bf16x8 kb = *(const bf16x8*)&Ks[(nt * 16 + c) * 64 + ((kh * 4 + g) ^ (c & 7)) * 8];
        s[0][nt] = __builtin_amdgcn_mfma_f32_16x16x32_bf16(kb, qa[0][kh], s[0][nt], 0, 0, 0);
        s[1][nt] = __builtin_amdgcn_mfma_f32_16x16x32_bf16(kb, qa[1][kh], s[1][nt], 0, 0, 0);
      }
    }

    __syncthreads();  // B1: all waves done reading Ks; drains V(jt) DMA
    if (jt + 1 < SEQ / 64) {  // DMA K(jt+1); softmax+PV time to land
      const int jb = (jt + 1) * 64;
      gl_lds16(Kk + base + (size_t)(jb + q0 * 8 + r8) * HDIM + gch * 8, &Ks[q0 * 8 * 64]);
      gl_lds16(Kk + base + (size_t)(jb + q1 * 8 + r8) * HDIM + gch * 8, &Ks[q1 * 8 * 64]);
    }

    // p = exp2(s); pack 4 consecutive j; plain stride-72 Pt, per group
#pragma unroll
    for (int nt = 0; nt < 4; nt++) {
      float a0 = __builtin_amdgcn_exp2f(s[0][nt][0]);
      float a1 = __builtin_amdgcn_exp2f(s[0][nt][1]);
      float a2 = __builtin_amdgcn_exp2f(s[0][nt][2]);
      float a3 = __builtin_amdgcn_exp2f(s[0][nt][3]);
      u32x2 pw0 = {pk2(a0, a1), pk2(a2, a3)};
      *(u32x2*)&Pt0[c * 72 + nt * 16 + g * 4] = pw0;
      float b0 = __builtin_amdgcn_exp2f(s[1][nt][0]);
      float b1 = __builtin_amdgcn_exp2f(s[1][nt][1]);
      float b2 = __builtin_amdgcn_exp2f(s[1][nt][2]);
      float b3 = __builtin_amdgcn_exp2f(s[1][nt][3]);
      u32x2 pw1 = {pk2(b0, b1), pk2(b2, b3)};
      *(u32x2*)&Pt1[c * 72 + nt * 16 + g * 4] = pw1;
    }
    bf16x8 pb[2][2];
    pb[0][0] = *(const bf16x8*)&Pt0[c * 72 + g * 8];
    pb[0][1] = *(const bf16x8*)&Pt0[c * 72 + 32 + g * 8];
    pb[1][0] = *(const bf16x8*)&Pt1[c * 72 + g * 8];
    pb[1][1] = *(const bf16x8*)&Pt1[c * 72 + 32 + g * 8];

    // O^T += V^T . P^T — each vb read feeds both q-groups;
    // l += ones . P^T in the MFMA pipe
#pragma unroll
    for (int dt = 0; dt < 4; dt++) {
      bf16x8 vb0 = *(const bf16x8*)&Vts[(dt * 16 + c) * 64 + ((0 + g) ^ (c & 7)) * 8];
      bf16x8 vb1 = *(const bf16x8*)&Vts[(dt * 16 + c) * 64 + ((4 + g) ^ (c & 7)) * 8];
      o[0][dt] = __builtin_amdgcn_mfma_f32_16x16x32_bf16(vb0, pb[0][0], o[0][dt], 0, 0, 0);
      o[0][dt] = __builtin_amdgcn_mfma_f32_16x16x32_bf16(vb1, pb[0][1], o[0][dt], 0, 0, 0);
      o[1][dt] = __builtin_amdgcn_mfma_f32_16x16x32_bf16(vb0, pb[1][0], o[1][dt], 0, 0, 0);
      o[1][dt] = __builtin_amdgcn_mfma_f32_16x16x32_bf16(vb1, pb[1][1], o[1][dt], 0, 0, 0);
    }
    o_l[0] = __builtin_amdgcn_mfma_f32_16x16x32_bf16(ones, pb[0][0], o_l[0], 0, 0, 0);
    o_l[0] = __builtin_amdgcn_mfma_f32_16x16x32_bf16(ones, pb[0][1], o_l[0], 0, 0, 0);
    o_l[1] = __builtin_amdgcn_mfma_f32_16x16x32_bf16(ones, pb[1][0], o_l[1], 0, 0, 0);
    o_l[1] = __builtin_amdgcn_mfma_f32_16x16x32_bf16(ones, pb[1][1], o_l[1], 0, 0, 0);

    __syncthreads();  // B2: all waves done reading Vts; drains K(jt+1) DMA
    if (jt + 1 < SEQ / 64) {  // DMA V(jt+1); S-phase time to land
      const int jb = (jt + 1) * 64;
      gl_lds16(V + base + (size_t)(q0 * 8 + r8) * SEQ + jb + gch * 8, &Vts[q0 * 8 * 64]);
      gl_lds16(V + base + (size_t)(q1 * 8 + r8) * SEQ + jb + gch * 8, &Vts[q1 * 8 * 64]);
    }
  }

  // epilogue: l[c] replicated in every o_l reg — no shuffles; packed stores
#pragma unroll
  for (int grp = 0; grp < 2; grp++) {
    const float inv = __builtin_amdgcn_rcpf(o_l[grp][0]);
    const int mb = grp ? mb1 : mb0;
    const size_t rowoff = ((size_t)bb * SEQ + mb + c) * EMBED + h * 64 + g * 4;
#pragma unroll
    for (int dt = 0; dt < 4; dt++) {
      s16x4 ov;
#pragma unroll
      for (int r = 0; r < 4; r++)
        ov[r] = (short)__bfloat16_as_ushort(f2b(o[grp][dt][r] * inv));
      *(s16x4*)&O[rowoff + dt * 16] = ov;
    }
  }
}

// ---------------------------------------------------------------------------
extern "C" void kernel_launch(void* const* d_in, const int* in_sizes, int n_in,
                              void* d_out, int out_size, void* d_ws,
                              size_t ws_size, hipStream_t stream) {
  const float* x      = (const float*)d_in[0];
  const float* w_qkv  = (const float*)d_in[1];
  const float* b_qkv  = (const float*)d_in[2];
  const float* w_proj = (const float*)d_in[3];
  const float* b_proj = (const float*)d_in[4];

  const size_t per = (size_t)BATCH * NHEAD * SEQ * HDIM;
  bf16* Qp = (bf16*)d_ws;
  bf16* Kp = Qp + per;
  bf16* Vp = Kp + per;                 // [B,H,D,N]
  bf16* xb = Vp + per;                 // x bf16; reused as AO after QKV GEMM
  bf16* wqkvb = xb + per;
  bf16* wprojb = wqkvb + (size_t)3 * EMBED * EMBED;
  bf16* AO = xb;

  const int ncvt = NX4 + NWQ4 + NWP4;  // f32x4 groups total
  cvt_all<<<dim3((ncvt + 255) / 256), 256, 0, stream>>>(x, w_qkv, w_proj, xb,
                                                        wqkvb, wprojb);

  // QKV GEMM: 256^2 tiles, 512 threads -> grid (9, 32) = 288 blocks
  dim3 g1(2304 / 256, 8192 / 256);
  gemm_qkv<<<g1, 512, 0, stream>>>(xb, wqkvb, b_qkv, Qp, Kp, Vp, EMBED);

  // 128 q-rows per block: B*H*(SEQ/128) = 768 blocks, 34.8 KB LDS
  attn_mfma<<<dim3(BATCH * NHEAD * (SEQ / 128)), 256, 0, stream>>>(Qp, Kp, Vp, AO);

  // proj GEMM: TM=64 -> grid (6,128)=768 blocks
  dim3 g2(768 / 128, 8192 / 64);
  gemm_proj<64><<<g2, 256, 0, stream>>>(AO, wprojb, b_proj, (float*)d_out,
                                        EMBED, EMBED);
}

// Round 7
// 230.758 us; speedup vs baseline: 1.0110x; 1.0110x over previous
//
#include <hip/hip_runtime.h>
#include <hip/hip_bf16.h>
#include <math.h>

#define EMBED 768
#define NHEAD 12
#define HDIM 64
#define SEQ 2048
#define BATCH 4

typedef __hip_bfloat16 bf16;
typedef __attribute__((ext_vector_type(8))) short bf16x8;   // 8 bf16 / 4 VGPRs
typedef __attribute__((ext_vector_type(4))) short s16x4;
typedef __attribute__((ext_vector_type(4))) float f32x4;
typedef __attribute__((ext_vector_type(2))) unsigned int u32x2;

__device__ inline float b2f(bf16 v) { return __bfloat162float(v); }
__device__ inline bf16 f2b(float v) { return __float2bfloat16(v); }
__device__ inline unsigned pk2(float a, float b) {
  return (unsigned)__bfloat16_as_ushort(f2b(a)) |
         ((unsigned)__bfloat16_as_ushort(f2b(b)) << 16);
}

// async global->LDS, 16B per lane. LDS dest = wave-uniform base + lane*16.
__device__ inline void gl_lds16(const bf16* g, bf16* l) {
  __builtin_amdgcn_global_load_lds(
      (const __attribute__((address_space(1))) void*)g,
      (__attribute__((address_space(3))) void*)l, 16, 0, 0);
}

#define NX4  (BATCH * SEQ * EMBED / 4)
#define NWQ4 (3 * EMBED * EMBED / 4)
#define NWP4 (EMBED * EMBED / 4)

// ---------------------------------------------------------------------------
// One fused f32->bf16 convert for x, w_qkv, w_proj (segmented index space).
// ---------------------------------------------------------------------------
__global__ __launch_bounds__(256) void cvt_all(
    const float* __restrict__ x, const float* __restrict__ wq,
    const float* __restrict__ wp, bf16* __restrict__ xb,
    bf16* __restrict__ wqb, bf16* __restrict__ wpb) {
  int i = blockIdx.x * 256 + threadIdx.x;
  const float* src;
  bf16* dst;
  int k;
  if (i < NX4) {
    src = x; dst = xb; k = i;
  } else if (i < NX4 + NWQ4) {
    src = wq; dst = wqb; k = i - NX4;
  } else if (i < NX4 + NWQ4 + NWP4) {
    src = wp; dst = wpb; k = i - NX4 - NWQ4;
  } else {
    return;
  }
  float4 v = ((const float4*)src)[k];
  s16x4 o;
  o[0] = (short)__bfloat16_as_ushort(f2b(v.x));
  o[1] = (short)__bfloat16_as_ushort(f2b(v.y));
  o[2] = (short)__bfloat16_as_ushort(f2b(v.z));
  o[3] = (short)__bfloat16_as_ushort(f2b(v.w));
  *(s16x4*)(dst + 4 * (size_t)k) = o;
}

// ---------------------------------------------------------------------------
// R19: QKV GEMM — LDS-ratio restructure. R6 post-mortem (per-CU arithmetic):
//   at 64x64 per-wave tiles the CU's ds_read_b128 stream (256/step at 4
//   blocks = ~3072 cy) exceeds MFMA (~1550 cy) — the kernel is LDS-READ-PORT
//   bound, which is why dbuf/vmcnt/occupancy tweaks (R3/R4/R5) were null.
//   Fix = raise MFMA-per-b128: 64x128 per-wave tile reads 24 b128 for 64
//   MFMA (2.67) vs 16 for 32 (2.0) -> -25% LDS bytes/FLOP.
//   Block = 128m x 256o, 4 waves (wave tile 64m x 128o), single-buffer
//   BK=64 with the R2-verified 2-barrier schedule (only schedule that ever
//   measured best). LDS 48KB -> 2-3 blocks/CU; grid 9x64=576 ~= 1 round at
//   2/CU. launch_bounds(256,2) caps VGPR at 256 (acc[8][4]=128 + frags).
//   o-span 256 divides 768 -> `which` (Q/K/V) is block-uniform.
// R14 (kept): BK=64, both-sides XOR swizzle — DMA source chunk
//   (lane&7)^(lane>>3), read slot (h*4+g)^(c&7); slot^row cancels (verif R2).
// Epilogue (verified R11/R12): Q(x 0.125*log2e)->[B,H,N,D], K->[B,H,N,D],
//   V->[B,H,D,N] (bf16).
// ---------------------------------------------------------------------------
__global__ __launch_bounds__(256, 2) void gemm_qkv(
    const bf16* __restrict__ A, const bf16* __restrict__ W,
    const float* __restrict__ bias, bf16* __restrict__ outQ,
    bf16* __restrict__ outK, bf16* __restrict__ outV, int K) {
  __shared__ bf16 As[128][64];   // 16 KB
  __shared__ bf16 Bs[256][64];   // 32 KB
  const int t = threadIdx.x;
  const int w = t >> 6;                // 0..3
  const int lane = t & 63;
  const int g = lane >> 4, c = lane & 15;
  const int m0 = blockIdx.y * 128, n0 = blockIdx.x * 256;
  const int wr = (w & 1) * 64;         // m-dim wave base (As): 64 rows
  const int wc = (w >> 1) * 128;       // o-dim wave base (Bs): 128 rows

  // DMA mapping: 1KB per instr = 8 rows x 128B. Source chunk pre-swizzled.
  const int srow = lane >> 3;          // 0..7 row within 8-row stripe
  const int l8 = lane & 7;             // LDS 16B-slot within row
  const int sseg = (l8 ^ srow) * 8;    // swizzled global chunk (bf16 elems)

  f32x4 acc[8][4] = {};   // acc[i][j]: i over o-frags (W), j over m-frags (x)

  for (int k0 = 0; k0 < K; k0 += 64) {
    // stage A: 128 rows = 4 waves x 4 rounds x 8 rows
#pragma unroll
    for (int i = 0; i < 4; i++) {
      int r = w * 32 + i * 8;
      gl_lds16(A + (size_t)(m0 + r + srow) * K + k0 + sseg, &As[r][0]);
    }
    // stage B: 256 rows = 4 waves x 8 rounds x 8 rows
#pragma unroll
    for (int i = 0; i < 8; i++) {
      int r = w * 64 + i * 8;
      gl_lds16(W + (size_t)(n0 + r + srow) * K + k0 + sseg, &Bs[r][0]);
    }
    __syncthreads();

#pragma unroll
    for (int h = 0; h < 2; h++) {
      bf16x8 xf[4], wf[8];
#pragma unroll
      for (int j = 0; j < 4; j++)
        xf[j] = *(const bf16x8*)&As[wr + j * 16 + c][((h * 4 + g) ^ (c & 7)) * 8];
#pragma unroll
      for (int i = 0; i < 8; i++)
        wf[i] = *(const bf16x8*)&Bs[wc + i * 16 + c][((h * 4 + g) ^ (c & 7)) * 8];
#pragma unroll
      for (int i = 0; i < 8; i++)
#pragma unroll
        for (int j = 0; j < 4; j++)
          acc[i][j] = __builtin_amdgcn_mfma_f32_16x16x32_bf16(wf[i], xf[j],
                                                              acc[i][j], 0, 0, 0);
    }
    __syncthreads();
  }

  // epilogue: D^T tile — row = o (4 consecutive per thread), col = m (lane c)
  // `which` is block-uniform: o-span 256 divides EMBED=768.
#pragma unroll
  for (int i = 0; i < 8; i++) {
    const int ob = n0 + wc + i * 16 + g * 4;     // o base, +r consecutive
    const f32x4 bv = *(const f32x4*)&bias[ob];   // 16B-aligned
    const int which = ob / EMBED;
    const int rem = ob - which * EMBED;
    const int hh = rem >> 6;
    const int d0 = rem & 63;
#pragma unroll
    for (int j = 0; j < 4; j++) {
      const int m = m0 + wr + j * 16 + c;
      f32x4 v = acc[i][j] + bv;
      const int bb = m >> 11, n = m & 2047;
      const size_t bh = (size_t)bb * NHEAD + hh;
      if (which == 0) {
        s16x4 q4;
#pragma unroll
        for (int r = 0; r < 4; r++)
          q4[r] = (short)__bfloat16_as_ushort(f2b(v[r] * 0.1803368801f));
        *(s16x4*)&outQ[(bh * SEQ + n) * HDIM + d0] = q4;
      } else if (which == 1) {
        s16x4 k4;
#pragma unroll
        for (int r = 0; r < 4; r++)
          k4[r] = (short)__bfloat16_as_ushort(f2b(v[r]));
        *(s16x4*)&outK[(bh * SEQ + n) * HDIM + d0] = k4;
      } else {
#pragma unroll
        for (int r = 0; r < 4; r++)
          outV[(bh * HDIM + d0 + r) * SEQ + n] = f2b(v[r]);
      }
    }
  }
}

// ---------------------------------------------------------------------------
// proj GEMM — R5-verified 128xTM structure (single-buf BK=64, 2 barriers,
// both-sides XOR swizzle, launch_bounds(256,4)). TM=64: grid 768 blocks.
// outF[m,o] f32 row-major.
// ---------------------------------------------------------------------------
template <int TM>
__global__ __launch_bounds__(256, 4) void gemm_proj(
    const bf16* __restrict__ A, const bf16* __restrict__ W,
    const float* __restrict__ bias, float* __restrict__ outF, int N, int K) {
  __shared__ bf16 As[TM][64];
  __shared__ bf16 Bs[128][64];
  const int t = threadIdx.x;
  const int w = t >> 6;
  const int lane = t & 63;
  const int g = lane >> 4, c = lane & 15;
  const int m0 = blockIdx.y * TM, n0 = blockIdx.x * 128;
  constexpr int MJ = TM / 32;          // m-frags per wave: 2 (TM=64)
  const int wr = (w >> 1) * (TM / 2);  // m-dim tile base (As)
  const int wc = (w & 1) * 64;         // o-dim tile base (Bs)

  const int srow = lane >> 3;
  const int l8 = lane & 7;
  const int sseg = (l8 ^ srow) * 8;

  f32x4 acc[4][MJ] = {};

  for (int k0 = 0; k0 < K; k0 += 64) {
#pragma unroll
    for (int i = 0; i < 4; i++) {
      int r = w * 32 + i * 8;
      gl_lds16(W + (size_t)(n0 + r + srow) * K + k0 + sseg, &Bs[r][0]);
    }
#pragma unroll
    for (int i = 0; i < TM / 32; i++) {
      int r = w * (TM / 4) + i * 8;
      gl_lds16(A + (size_t)(m0 + r + srow) * K + k0 + sseg, &As[r][0]);
    }
    __syncthreads();

#pragma unroll
    for (int h = 0; h < 2; h++) {
      bf16x8 xf[MJ], wf[4];
#pragma unroll
      for (int j = 0; j < MJ; j++)
        xf[j] = *(const bf16x8*)&As[wr + j * 16 + c][((h * 4 + g) ^ (c & 7)) * 8];
#pragma unroll
      for (int i = 0; i < 4; i++)
        wf[i] = *(const bf16x8*)&Bs[wc + i * 16 + c][((h * 4 + g) ^ (c & 7)) * 8];
#pragma unroll
      for (int i = 0; i < 4; i++)
#pragma unroll
        for (int j = 0; j < MJ; j++)
          acc[i][j] = __builtin_amdgcn_mfma_f32_16x16x32_bf16(wf[i], xf[j],
                                                              acc[i][j], 0, 0, 0);
    }
    __syncthreads();
  }

#pragma unroll
  for (int i = 0; i < 4; i++) {
    const int ob = n0 + wc + i * 16 + g * 4;
    const f32x4 bv = *(const f32x4*)&bias[ob];
#pragma unroll
    for (int j = 0; j < MJ; j++) {
      const int m = m0 + wr + j * 16 + c;
      f32x4 v = acc[i][j] + bv;
      *(f32x4*)&outF[(size_t)m * N + ob] = v;
    }
  }
}

// ---------------------------------------------------------------------------
// Flash MFMA attention v7 — measured-best structure (82.3-83.4 µs), FROZEN.
// R14 post-mortem: v8 (dbuf + single barrier + setprio) was NULL-to-negative
// (84.7 µs) — attn is not barrier/drain-bound; plateau is structural
// (LDS traffic + 3 waves/SIMD latency hiding).
//   S^T = K . Q^T ; O^T = V^T . P^T  (fragment maps verified R3-R12)
// Block = 128 q-rows, 4 waves x 2 groups of 16. LDS 34.8 KB; grid 768 = 3/CU.
// Per iter: S(ks) -> B1 -> DMA K(jt+1) -> softmax/Pt/PV(vs) -> B2 -> DMA V(jt+1).
// ---------------------------------------------------------------------------
__global__ __launch_bounds__(256, 4) void attn_mfma(
    const bf16* __restrict__ Q, const bf16* __restrict__ Kk,
    const bf16* __restrict__ V, bf16* __restrict__ O) {
  __shared__ bf16 Ks[64 * 64];
  __shared__ bf16 Vts[64 * 64];
  __shared__ bf16 Pt[8][16 * 72];

  const int blk = blockIdx.x;
  const int bh = blk >> 4;               // 16 q-tiles (of 128) per (b,h)
  const int qt = blk & 15;
  const int bb = bh / NHEAD;
  const int h = bh % NHEAD;
  const int t = threadIdx.x;
  const int lane = t & 63;
  const int w = t >> 6;
  const int g = lane >> 4;
  const int c = lane & 15;
  const size_t base = (size_t)bh * SEQ * HDIM;
  const int mb0 = qt * 128 + w * 16;     // q-group 0 rows
  const int mb1 = mb0 + 64;              // q-group 1 rows

  // DMA lane mapping (XOR chunk swizzle for K/V, verified R5-R12)
  const int r8 = lane >> 3;
  const int l8 = lane & 7;
  const int gch = l8 ^ (r8 & 7);
  const int q0 = w * 2, q1 = w * 2 + 1;

  // Q fragments (B operand), one pair per q-group
  bf16x8 qa[2][2];
#pragma unroll
  for (int kh = 0; kh < 2; kh++) {
    qa[0][kh] = *(const bf16x8*)(Q + base + (size_t)(mb0 + c) * HDIM + kh * 32 + g * 8);
    qa[1][kh] = *(const bf16x8*)(Q + base + (size_t)(mb1 + c) * HDIM + kh * 32 + g * 8);
  }

  // all-ones A fragment for the l-row-sum MFMA
  bf16x8 ones;
#pragma unroll
  for (int i = 0; i < 8; i++) ones[i] = (short)0x3F80;

  f32x4 o[2][4] = {};
  f32x4 o_l[2] = {};

  // prologue: DMA tile 0 (K and V), drain before first use
  gl_lds16(Kk + base + (size_t)(q0 * 8 + r8) * HDIM + gch * 8, &Ks[q0 * 8 * 64]);
  gl_lds16(Kk + base + (size_t)(q1 * 8 + r8) * HDIM + gch * 8, &Ks[q1 * 8 * 64]);
  gl_lds16(V + base + (size_t)(q0 * 8 + r8) * SEQ + gch * 8, &Vts[q0 * 8 * 64]);
  gl_lds16(V + base + (size_t)(q1 * 8 + r8) * SEQ + gch * 8, &Vts[q1 * 8 * 64]);
  __syncthreads();

  bf16* const Pt0 = Pt[w * 2];
  bf16* const Pt1 = Pt[w * 2 + 1];

  for (int jt = 0; jt < SEQ / 64; jt++) {
    // S^T = K . Q^T — each kb read feeds both q-groups
    f32x4 s[2][4] = {};
#pragma unroll
    for (int nt = 0; nt < 4; nt++) {
#pragma unroll
      for (int kh = 0; kh < 2; kh++) {
        bf16x8 kb = *(const bf16x8*)&Ks[(nt * 16 + c) * 64 + ((kh * 4 + g) ^ (c & 7)) * 8];
        s[0][nt] = __builtin_amdgcn_mfma_f32_16x16x32_bf16(kb, qa[0][kh], s[0][nt], 0, 0, 0);
        s[1][nt] = __builtin_amdgcn_mfma_f32_16x16x32_bf16(kb, qa[1][kh], s[1][nt], 0, 0, 0);
      }
    }

    __syncthreads();  // B1: all waves done reading Ks; drains V(jt) DMA
    if (jt + 1 < SEQ / 64) {  // DMA K(jt+1); softmax+PV time to land
      const int jb = (jt + 1) * 64;
      gl_lds16(Kk + base + (size_t)(jb + q0 * 8 + r8) * HDIM + gch * 8, &Ks[q0 * 8 * 64]);
      gl_lds16(Kk + base + (size_t)(jb + q1 * 8 + r8) * HDIM + gch * 8, &Ks[q1 * 8 * 64]);
    }

    // p = exp2(s); pack 4 consecutive j; plain stride-72 Pt, per group
#pragma unroll
    for (int nt = 0; nt < 4; nt++) {
      float a0 = __builtin_amdgcn_exp2f(s[0][nt][0]);
      float a1 = __builtin_amdgcn_exp2f(s[0][nt][1]);
      float a2 = __builtin_amdgcn_exp2f(s[0][nt][2]);
      float a3 = __builtin_amdgcn_exp2f(s[0][nt][3]);
      u32x2 pw0 = {pk2(a0, a1), pk2(a2, a3)};
      *(u32x2*)&Pt0[c * 72 + nt * 16 + g * 4] = pw0;
      float b0 = __builtin_amdgcn_exp2f(s[1][nt][0]);
      float b1 = __builtin_amdgcn_exp2f(s[1][nt][1]);
      float b2 = __builtin_amdgcn_exp2f(s[1][nt][2]);
      float b3 = __builtin_amdgcn_exp2f(s[1][nt][3]);
      u32x2 pw1 = {pk2(b0, b1), pk2(b2, b3)};
      *(u32x2*)&Pt1[c * 72 + nt * 16 + g * 4] = pw1;
    }
    bf16x8 pb[2][2];
    pb[0][0] = *(const bf16x8*)&Pt0[c * 72 + g * 8];
    pb[0][1] = *(const bf16x8*)&Pt0[c * 72 + 32 + g * 8];
    pb[1][0] = *(const bf16x8*)&Pt1[c * 72 + g * 8];
    pb[1][1] = *(const bf16x8*)&Pt1[c * 72 + 32 + g * 8];

    // O^T += V^T . P^T — each vb read feeds both q-groups;
    // l += ones . P^T in the MFMA pipe
#pragma unroll
    for (int dt = 0; dt < 4; dt++) {
      bf16x8 vb0 = *(const bf16x8*)&Vts[(dt * 16 + c) * 64 + ((0 + g) ^ (c & 7)) * 8];
      bf16x8 vb1 = *(const bf16x8*)&Vts[(dt * 16 + c) * 64 + ((4 + g) ^ (c & 7)) * 8];
      o[0][dt] = __builtin_amdgcn_mfma_f32_16x16x32_bf16(vb0, pb[0][0], o[0][dt], 0, 0, 0);
      o[0][dt] = __builtin_amdgcn_mfma_f32_16x16x32_bf16(vb1, pb[0][1], o[0][dt], 0, 0, 0);
      o[1][dt] = __builtin_amdgcn_mfma_f32_16x16x32_bf16(vb0, pb[1][0], o[1][dt], 0, 0, 0);
      o[1][dt] = __builtin_amdgcn_mfma_f32_16x16x32_bf16(vb1, pb[1][1], o[1][dt], 0, 0, 0);
    }
    o_l[0] = __builtin_amdgcn_mfma_f32_16x16x32_bf16(ones, pb[0][0], o_l[0], 0, 0, 0);
    o_l[0] = __builtin_amdgcn_mfma_f32_16x16x32_bf16(ones, pb[0][1], o_l[0], 0, 0, 0);
    o_l[1] = __builtin_amdgcn_mfma_f32_16x16x32_bf16(ones, pb[1][0], o_l[1], 0, 0, 0);
    o_l[1] = __builtin_amdgcn_mfma_f32_16x16x32_bf16(ones, pb[1][1], o_l[1], 0, 0, 0);

    __syncthreads();  // B2: all waves done reading Vts; drains K(jt+1) DMA
    if (jt + 1 < SEQ / 64) {  // DMA V(jt+1); S-phase time to land
      const int jb = (jt + 1) * 64;
      gl_lds16(V + base + (size_t)(q0 * 8 + r8) * SEQ + jb + gch * 8, &Vts[q0 * 8 * 64]);
      gl_lds16(V + base + (size_t)(q1 * 8 + r8) * SEQ + jb + gch * 8, &Vts[q1 * 8 * 64]);
    }
  }

  // epilogue: l[c] replicated in every o_l reg — no shuffles; packed stores
#pragma unroll
  for (int grp = 0; grp < 2; grp++) {
    const float inv = __builtin_amdgcn_rcpf(o_l[grp][0]);
    const int mb = grp ? mb1 : mb0;
    const size_t rowoff = ((size_t)bb * SEQ + mb + c) * EMBED + h * 64 + g * 4;
#pragma unroll
    for (int dt = 0; dt < 4; dt++) {
      s16x4 ov;
#pragma unroll
      for (int r = 0; r < 4; r++)
        ov[r] = (short)__bfloat16_as_ushort(f2b(o[grp][dt][r] * inv));
      *(s16x4*)&O[rowoff + dt * 16] = ov;
    }
  }
}

// ---------------------------------------------------------------------------
extern "C" void kernel_launch(void* const* d_in, const int* in_sizes, int n_in,
                              void* d_out, int out_size, void* d_ws,
                              size_t ws_size, hipStream_t stream) {
  const float* x      = (const float*)d_in[0];
  const float* w_qkv  = (const float*)d_in[1];
  const float* b_qkv  = (const float*)d_in[2];
  const float* w_proj = (const float*)d_in[3];
  const float* b_proj = (const float*)d_in[4];

  const size_t per = (size_t)BATCH * NHEAD * SEQ * HDIM;
  bf16* Qp = (bf16*)d_ws;
  bf16* Kp = Qp + per;
  bf16* Vp = Kp + per;                 // [B,H,D,N]
  bf16* xb = Vp + per;                 // x bf16; reused as AO after QKV GEMM
  bf16* wqkvb = xb + per;
  bf16* wprojb = wqkvb + (size_t)3 * EMBED * EMBED;
  bf16* AO = xb;

  const int ncvt = NX4 + NWQ4 + NWP4;  // f32x4 groups total
  cvt_all<<<dim3((ncvt + 255) / 256), 256, 0, stream>>>(x, w_qkv, w_proj, xb,
                                                        wqkvb, wprojb);

  // QKV GEMM: block 128m x 256o, 4 waves -> grid (9, 64) = 576 blocks
  dim3 g1(2304 / 256, 8192 / 128);
  gemm_qkv<<<g1, 256, 0, stream>>>(xb, wqkvb, b_qkv, Qp, Kp, Vp, EMBED);

  // 128 q-rows per block: B*H*(SEQ/128) = 768 blocks, 34.8 KB LDS
  attn_mfma<<<dim3(BATCH * NHEAD * (SEQ / 128)), 256, 0, stream>>>(Qp, Kp, Vp, AO);

  // proj GEMM: TM=64 -> grid (6,128)=768 blocks
  dim3 g2(768 / 128, 8192 / 64);
  gemm_proj<64><<<g2, 256, 0, stream>>>(AO, wprojb, b_proj, (float*)d_out,
                                        EMBED, EMBED);
}

// Round 8
// 212.215 us; speedup vs baseline: 1.0993x; 1.0874x over previous
//
#include <hip/hip_runtime.h>
#include <hip/hip_bf16.h>
#include <math.h>

#define EMBED 768
#define NHEAD 12
#define HDIM 64
#define SEQ 2048
#define BATCH 4

typedef __hip_bfloat16 bf16;
typedef __attribute__((ext_vector_type(8))) short bf16x8;   // 8 bf16 / 4 VGPRs
typedef __attribute__((ext_vector_type(4))) short s16x4;
typedef __attribute__((ext_vector_type(4))) float f32x4;
typedef __attribute__((ext_vector_type(2))) unsigned int u32x2;

__device__ inline float b2f(bf16 v) { return __bfloat162float(v); }
__device__ inline bf16 f2b(float v) { return __float2bfloat16(v); }
__device__ inline unsigned pk2(float a, float b) {
  return (unsigned)__bfloat16_as_ushort(f2b(a)) |
         ((unsigned)__bfloat16_as_ushort(f2b(b)) << 16);
}

// async global->LDS, 16B per lane. LDS dest = wave-uniform base + lane*16.
__device__ inline void gl_lds16(const bf16* g, bf16* l) {
  __builtin_amdgcn_global_load_lds(
      (const __attribute__((address_space(1))) void*)g,
      (__attribute__((address_space(3))) void*)l, 16, 0, 0);
}

#define NX4  (BATCH * SEQ * EMBED / 4)
#define NWQ4 (3 * EMBED * EMBED / 4)
#define NWP4 (EMBED * EMBED / 4)

// ---------------------------------------------------------------------------
// One fused f32->bf16 convert for x, w_qkv, w_proj (segmented index space).
// ---------------------------------------------------------------------------
__global__ __launch_bounds__(256) void cvt_all(
    const float* __restrict__ x, const float* __restrict__ wq,
    const float* __restrict__ wp, bf16* __restrict__ xb,
    bf16* __restrict__ wqb, bf16* __restrict__ wpb) {
  int i = blockIdx.x * 256 + threadIdx.x;
  const float* src;
  bf16* dst;
  int k;
  if (i < NX4) {
    src = x; dst = xb; k = i;
  } else if (i < NX4 + NWQ4) {
    src = wq; dst = wqb; k = i - NX4;
  } else if (i < NX4 + NWQ4 + NWP4) {
    src = wp; dst = wpb; k = i - NX4 - NWQ4;
  } else {
    return;
  }
  float4 v = ((const float4*)src)[k];
  s16x4 o;
  o[0] = (short)__bfloat16_as_ushort(f2b(v.x));
  o[1] = (short)__bfloat16_as_ushort(f2b(v.y));
  o[2] = (short)__bfloat16_as_ushort(f2b(v.z));
  o[3] = (short)__bfloat16_as_ushort(f2b(v.w));
  *(s16x4*)(dst + 4 * (size_t)k) = o;
}

// ---------------------------------------------------------------------------
// MFMA GEMM, operand-swapped (computes C^T tiles). R5-EXACT loop/schedule
// (single-buf BK=64, 2 barriers/step, both-sides XOR swizzle — the measured
// best; R3/R4/R6/R7 alternatives all null-to-negative, reverted).
// R20: 1D launch + XCD L2-locality swizzle ONLY (index bijection, schedule
//   untouched). Mechanism: staging-DMA drains are L2-hit (~200cy) vs miss
//   (~900cy); un-swizzled round-robin gives each XCD a ~13MB working set
//   (>4MB L2). Chunking m-rows per XCD shrinks it to ~5.1MB (gemm0) /
//   ~2.8MB (proj).
//   MODE 0 (TM=128): grid 1152 = 18 n-tiles x 64 m-rows; XCD k <- m-rows
//     [8k, 8k+8) x all n.   xcd=bid&7; idx=bid>>3; mr=xcd*8+idx/18; nc=idx%18.
//   MODE 1 (TM=64):  grid 768 = 6 n-tiles x 128 m-rows; XCD k <- m-rows
//     [16k,16k+16) x all n. xcd=bid&7; idx=bid>>3; mr=xcd*16+idx/6; nc=idx%6.
// MODE 0 epilogue (verified R11/R12): Q(x 0.125*log2e)->[B,H,N,D],
// K->[B,H,N,D], V->[B,H,D,N] (bf16).  MODE 1: outF[m,o] f32 row-major.
// WPB: min waves/EU (4 -> 4 blocks/CU @~116 VGPR; proj 5 @ <=102 VGPR, 24KB).
// ---------------------------------------------------------------------------
template <int MODE, int TM, int WPB>
__global__ __launch_bounds__(256, WPB) void gemm_mfma(
    const bf16* __restrict__ A, const bf16* __restrict__ W,
    const float* __restrict__ bias, float* __restrict__ outF,
    bf16* __restrict__ outQ, bf16* __restrict__ outK, bf16* __restrict__ outV,
    int M, int N, int K) {
  __shared__ bf16 As[TM][64];
  __shared__ bf16 Bs[128][64];
  const int t = threadIdx.x;
  const int w = t >> 6;
  const int lane = t & 63;
  const int g = lane >> 4, c = lane & 15;

  // XCD locality decode (bijective; see header comment)
  const int bid = blockIdx.x;
  const int xcd = bid & 7;
  const int idx = bid >> 3;
  constexpr int NT = (MODE == 0) ? 18 : 6;          // n-tiles
  constexpr int MRX = (MODE == 0) ? 8 : 16;         // m-rows per XCD
  const int mr = xcd * MRX + idx / NT;
  const int nc = idx % NT;
  const int m0 = mr * TM, n0 = nc * 128;

  constexpr int MJ = TM / 32;          // m-frags per wave: 4 (TM=128) / 2 (64)
  const int wr = (w >> 1) * (TM / 2);  // m-dim tile base (As)
  const int wc = (w & 1) * 64;         // o-dim tile base (Bs)

  // DMA mapping: 1KB per instr = 8 rows x 128B. Source chunk pre-swizzled.
  const int srow = lane >> 3;          // 0..7 row within 8-row stripe
  const int l8 = lane & 7;             // LDS 16B-slot within row
  const int sseg = (l8 ^ srow) * 8;    // swizzled global chunk (bf16 elems)

  f32x4 acc[4][MJ] = {};  // acc[i][j]: i over o-tiles (W), j over m-tiles (x)

  for (int k0 = 0; k0 < K; k0 += 64) {
#pragma unroll
    for (int i = 0; i < 4; i++) {
      int r = w * 32 + i * 8;
      gl_lds16(W + (size_t)(n0 + r + srow) * K + k0 + sseg, &Bs[r][0]);
    }
#pragma unroll
    for (int i = 0; i < TM / 32; i++) {
      int r = w * (TM / 4) + i * 8;
      gl_lds16(A + (size_t)(m0 + r + srow) * K + k0 + sseg, &As[r][0]);
    }
    __syncthreads();

#pragma unroll
    for (int h = 0; h < 2; h++) {
      bf16x8 xf[MJ], wf[4];
#pragma unroll
      for (int j = 0; j < MJ; j++)
        xf[j] = *(const bf16x8*)&As[wr + j * 16 + c][((h * 4 + g) ^ (c & 7)) * 8];
#pragma unroll
      for (int i = 0; i < 4; i++)
        wf[i] = *(const bf16x8*)&Bs[wc + i * 16 + c][((h * 4 + g) ^ (c & 7)) * 8];
#pragma unroll
      for (int i = 0; i < 4; i++)
#pragma unroll
        for (int j = 0; j < MJ; j++)
          acc[i][j] = __builtin_amdgcn_mfma_f32_16x16x32_bf16(wf[i], xf[j],
                                                              acc[i][j], 0, 0, 0);
    }
    __syncthreads();
  }

  // epilogue: D^T tile — row = o (4 consecutive per thread), col = m (lane c)
#pragma unroll
  for (int i = 0; i < 4; i++) {
    const int ob = n0 + wc + i * 16 + g * 4;     // o base, +r consecutive
    const f32x4 bv = *(const f32x4*)&bias[ob];   // 16B-aligned
    int which = 0, hh = 0, d0 = 0;
    if (MODE == 0) {
      which = ob / EMBED;
      int rem = ob - which * EMBED;
      hh = rem >> 6;
      d0 = rem & 63;
    }
#pragma unroll
    for (int j = 0; j < MJ; j++) {
      const int m = m0 + wr + j * 16 + c;
      f32x4 v = acc[i][j] + bv;
      if (MODE == 0) {
        const int bb = m >> 11, n = m & 2047;
        const size_t bh = (size_t)bb * NHEAD + hh;
        if (which == 0) {
          s16x4 q4;
#pragma unroll
          for (int r = 0; r < 4; r++)
            q4[r] = (short)__bfloat16_as_ushort(f2b(v[r] * 0.1803368801f));
          *(s16x4*)&outQ[(bh * SEQ + n) * HDIM + d0] = q4;
        } else if (which == 1) {
          s16x4 k4;
#pragma unroll
          for (int r = 0; r < 4; r++)
            k4[r] = (short)__bfloat16_as_ushort(f2b(v[r]));
          *(s16x4*)&outK[(bh * SEQ + n) * HDIM + d0] = k4;
        } else {
#pragma unroll
          for (int r = 0; r < 4; r++)
            outV[(bh * HDIM + d0 + r) * SEQ + n] = f2b(v[r]);
        }
      } else {
        *(f32x4*)&outF[(size_t)m * N + ob] = v;
      }
    }
  }
}

// ---------------------------------------------------------------------------
// Flash MFMA attention v7 — measured-best structure, FROZEN since R2.
// R20: XCD L2-locality swizzle (index bijection only): the 16 q-tile blocks
//   of one (b,h) share 512KB K/V; un-swizzled they scatter over all 8 XCDs
//   -> per-XCD K/V set 48bh x 512KB ~ 25MB >> 4MB L2 (FETCH 104MB confirms).
//   Map XCD = bh&7 via bid = (bh&7) + 8*(qt + 16*(bh>>3)): per-XCD set =
//   6bh x 512KB = 3MB -> staging DMAs become L2 hits, drains shrink.
//   Decode: lo=bid&7; rem=bid>>3; qt=rem&15; bh=(rem>>4)*8+lo.
//   S^T = K . Q^T ; O^T = V^T . P^T  (fragment maps verified R3-R12)
// Block = 128 q-rows, 4 waves x 2 groups of 16. LDS 34.8 KB; grid 768 = 3/CU.
// Per iter: S(ks) -> B1 -> DMA K(jt+1) -> softmax/Pt/PV(vs) -> B2 -> DMA V(jt+1).
// ---------------------------------------------------------------------------
__global__ __launch_bounds__(256, 4) void attn_mfma(
    const bf16* __restrict__ Q, const bf16* __restrict__ Kk,
    const bf16* __restrict__ V, bf16* __restrict__ O) {
  __shared__ bf16 Ks[64 * 64];
  __shared__ bf16 Vts[64 * 64];
  __shared__ bf16 Pt[8][16 * 72];

  const int bid = blockIdx.x;
  const int lo = bid & 7;
  const int rem = bid >> 3;
  const int qt = rem & 15;
  const int bh = (rem >> 4) * 8 + lo;    // XCD (bid&7) <- bh&7
  const int bb = bh / NHEAD;
  const int h = bh % NHEAD;
  const int t = threadIdx.x;
  const int lane = t & 63;
  const int w = t >> 6;
  const int g = lane >> 4;
  const int c = lane & 15;
  const size_t base = (size_t)bh * SEQ * HDIM;
  const int mb0 = qt * 128 + w * 16;     // q-group 0 rows
  const int mb1 = mb0 + 64;              // q-group 1 rows

  // DMA lane mapping (XOR chunk swizzle for K/V, verified R5-R12)
  const int r8 = lane >> 3;
  const int l8 = lane & 7;
  const int gch = l8 ^ (r8 & 7);
  const int q0 = w * 2, q1 = w * 2 + 1;

  // Q fragments (B operand), one pair per q-group
  bf16x8 qa[2][2];
#pragma unroll
  for (int kh = 0; kh < 2; kh++) {
    qa[0][kh] = *(const bf16x8*)(Q + base + (size_t)(mb0 + c) * HDIM + kh * 32 + g * 8);
    qa[1][kh] = *(const bf16x8*)(Q + base + (size_t)(mb1 + c) * HDIM + kh * 32 + g * 8);
  }

  // all-ones A fragment for the l-row-sum MFMA
  bf16x8 ones;
#pragma unroll
  for (int i = 0; i < 8; i++) ones[i] = (short)0x3F80;

  f32x4 o[2][4] = {};
  f32x4 o_l[2] = {};

  // prologue: DMA tile 0 (K and V), drain before first use
  gl_lds16(Kk + base + (size_t)(q0 * 8 + r8) * HDIM + gch * 8, &Ks[q0 * 8 * 64]);
  gl_lds16(Kk + base + (size_t)(q1 * 8 + r8) * HDIM + gch * 8, &Ks[q1 * 8 * 64]);
  gl_lds16(V + base + (size_t)(q0 * 8 + r8) * SEQ + gch * 8, &Vts[q0 * 8 * 64]);
  gl_lds16(V + base + (size_t)(q1 * 8 + r8) * SEQ + gch * 8, &Vts[q1 * 8 * 64]);
  __syncthreads();

  bf16* const Pt0 = Pt[w * 2];
  bf16* const Pt1 = Pt[w * 2 + 1];

  for (int jt = 0; jt < SEQ / 64; jt++) {
    // S^T = K . Q^T — each kb read feeds both q-groups
    f32x4 s[2][4] = {};
#pragma unroll
    for (int nt = 0; nt < 4; nt++) {
#pragma unroll
      for (int kh = 0; kh < 2; kh++) {
        bf16x8 kb = *(const bf16x8*)&Ks[(nt * 16 + c) * 64 + ((kh * 4 + g) ^ (c & 7)) * 8];
        s[0][nt] = __builtin_amdgcn_mfma_f32_16x16x32_bf16(kb, qa[0][kh], s[0][nt], 0, 0, 0);
        s[1][nt] = __builtin_amdgcn_mfma_f32_16x16x32_bf16(kb, qa[1][kh], s[1][nt], 0, 0, 0);
      }
    }

    __syncthreads();  // B1: all waves done reading Ks; drains V(jt) DMA
    if (jt + 1 < SEQ / 64) {  // DMA K(jt+1); softmax+PV time to land
      const int jb = (jt + 1) * 64;
      gl_lds16(Kk + base + (size_t)(jb + q0 * 8 + r8) * HDIM + gch * 8, &Ks[q0 * 8 * 64]);
      gl_lds16(Kk + base + (size_t)(jb + q1 * 8 + r8) * HDIM + gch * 8, &Ks[q1 * 8 * 64]);
    }

    // p = exp2(s); pack 4 consecutive j; plain stride-72 Pt, per group
#pragma unroll
    for (int nt = 0; nt < 4; nt++) {
      float a0 = __builtin_amdgcn_exp2f(s[0][nt][0]);
      float a1 = __builtin_amdgcn_exp2f(s[0][nt][1]);
      float a2 = __builtin_amdgcn_exp2f(s[0][nt][2]);
      float a3 = __builtin_amdgcn_exp2f(s[0][nt][3]);
      u32x2 pw0 = {pk2(a0, a1), pk2(a2, a3)};
      *(u32x2*)&Pt0[c * 72 + nt * 16 + g * 4] = pw0;
      float b0 = __builtin_amdgcn_exp2f(s[1][nt][0]);
      float b1 = __builtin_amdgcn_exp2f(s[1][nt][1]);
      float b2 = __builtin_amdgcn_exp2f(s[1][nt][2]);
      float b3 = __builtin_amdgcn_exp2f(s[1][nt][3]);
      u32x2 pw1 = {pk2(b0, b1), pk2(b2, b3)};
      *(u32x2*)&Pt1[c * 72 + nt * 16 + g * 4] = pw1;
    }
    bf16x8 pb[2][2];
    pb[0][0] = *(const bf16x8*)&Pt0[c * 72 + g * 8];
    pb[0][1] = *(const bf16x8*)&Pt0[c * 72 + 32 + g * 8];
    pb[1][0] = *(const bf16x8*)&Pt1[c * 72 + g * 8];
    pb[1][1] = *(const bf16x8*)&Pt1[c * 72 + 32 + g * 8];

    // O^T += V^T . P^T — each vb read feeds both q-groups;
    // l += ones . P^T in the MFMA pipe
#pragma unroll
    for (int dt = 0; dt < 4; dt++) {
      bf16x8 vb0 = *(const bf16x8*)&Vts[(dt * 16 + c) * 64 + ((0 + g) ^ (c & 7)) * 8];
      bf16x8 vb1 = *(const bf16x8*)&Vts[(dt * 16 + c) * 64 + ((4 + g) ^ (c & 7)) * 8];
      o[0][dt] = __builtin_amdgcn_mfma_f32_16x16x32_bf16(vb0, pb[0][0], o[0][dt], 0, 0, 0);
      o[0][dt] = __builtin_amdgcn_mfma_f32_16x16x32_bf16(vb1, pb[0][1], o[0][dt], 0, 0, 0);
      o[1][dt] = __builtin_amdgcn_mfma_f32_16x16x32_bf16(vb0, pb[1][0], o[1][dt], 0, 0, 0);
      o[1][dt] = __builtin_amdgcn_mfma_f32_16x16x32_bf16(vb1, pb[1][1], o[1][dt], 0, 0, 0);
    }
    o_l[0] = __builtin_amdgcn_mfma_f32_16x16x32_bf16(ones, pb[0][0], o_l[0], 0, 0, 0);
    o_l[0] = __builtin_amdgcn_mfma_f32_16x16x32_bf16(ones, pb[0][1], o_l[0], 0, 0, 0);
    o_l[1] = __builtin_amdgcn_mfma_f32_16x16x32_bf16(ones, pb[1][0], o_l[1], 0, 0, 0);
    o_l[1] = __builtin_amdgcn_mfma_f32_16x16x32_bf16(ones, pb[1][1], o_l[1], 0, 0, 0);

    __syncthreads();  // B2: all waves done reading Vts; drains K(jt+1) DMA
    if (jt + 1 < SEQ / 64) {  // DMA V(jt+1); S-phase time to land
      const int jb = (jt + 1) * 64;
      gl_lds16(V + base + (size_t)(q0 * 8 + r8) * SEQ + jb + gch * 8, &Vts[q0 * 8 * 64]);
      gl_lds16(V + base + (size_t)(q1 * 8 + r8) * SEQ + jb + gch * 8, &Vts[q1 * 8 * 64]);
    }
  }

  // epilogue: l[c] replicated in every o_l reg — no shuffles; packed stores
#pragma unroll
  for (int grp = 0; grp < 2; grp++) {
    const float inv = __builtin_amdgcn_rcpf(o_l[grp][0]);
    const int mb = grp ? mb1 : mb0;
    const size_t rowoff = ((size_t)bb * SEQ + mb + c) * EMBED + h * 64 + g * 4;
#pragma unroll
    for (int dt = 0; dt < 4; dt++) {
      s16x4 ov;
#pragma unroll
      for (int r = 0; r < 4; r++)
        ov[r] = (short)__bfloat16_as_ushort(f2b(o[grp][dt][r] * inv));
      *(s16x4*)&O[rowoff + dt * 16] = ov;
    }
  }
}

// ---------------------------------------------------------------------------
extern "C" void kernel_launch(void* const* d_in, const int* in_sizes, int n_in,
                              void* d_out, int out_size, void* d_ws,
                              size_t ws_size, hipStream_t stream) {
  const float* x      = (const float*)d_in[0];
  const float* w_qkv  = (const float*)d_in[1];
  const float* b_qkv  = (const float*)d_in[2];
  const float* w_proj = (const float*)d_in[3];
  const float* b_proj = (const float*)d_in[4];

  const size_t per = (size_t)BATCH * NHEAD * SEQ * HDIM;
  bf16* Qp = (bf16*)d_ws;
  bf16* Kp = Qp + per;
  bf16* Vp = Kp + per;                 // [B,H,D,N]
  bf16* xb = Vp + per;                 // x bf16; reused as AO after QKV GEMM
  bf16* wqkvb = xb + per;
  bf16* wprojb = wqkvb + (size_t)3 * EMBED * EMBED;
  bf16* AO = xb;

  const int ncvt = NX4 + NWQ4 + NWP4;  // f32x4 groups total
  cvt_all<<<dim3((ncvt + 255) / 256), 256, 0, stream>>>(x, w_qkv, w_proj, xb,
                                                        wqkvb, wprojb);

  // QKV GEMM: R5 structure, 1D grid 1152 (18 n x 64 m), XCD m-row chunking
  gemm_mfma<0, 128, 4><<<dim3(1152), 256, 0, stream>>>(
      xb, wqkvb, b_qkv, nullptr, Qp, Kp, Vp, BATCH * SEQ, 3 * EMBED, EMBED);

  // attn: 768 blocks, XCD = bh&7 (K/V L2-resident per XCD)
  attn_mfma<<<dim3(BATCH * NHEAD * (SEQ / 128)), 256, 0, stream>>>(Qp, Kp, Vp, AO);

  // proj GEMM: 1D grid 768 (6 n x 128 m), XCD m-row chunking, 5 blocks/CU
  gemm_mfma<1, 64, 5><<<dim3(768), 256, 0, stream>>>(
      AO, wprojb, b_proj, (float*)d_out, nullptr, nullptr, nullptr,
      BATCH * SEQ, EMBED, EMBED);
}